// Round 23
// baseline (79.160 us; speedup 1.0000x reference)
//
#include <hip/hip_runtime.h>
#include <hip/hip_bf16.h>
#include <cstdint>
#include <cmath>

#define N_PIX 4096
#define CH    128
#define DD    64
#define NBATCH 8
#define NT    32    // 4096 / 128 key-tiles

typedef unsigned short u16;
typedef __attribute__((ext_vector_type(8))) short bf8_t;
typedef __attribute__((ext_vector_type(4))) float f4_t;
typedef __attribute__((ext_vector_type(16))) float f16v;
typedef uint32_t u32x4 __attribute__((ext_vector_type(4)));
typedef uint32_t u32x2 __attribute__((ext_vector_type(2)));

#define L2E 1.44269504088896340736f

#if __has_builtin(__builtin_amdgcn_exp2f)
  #define EXP2(x) __builtin_amdgcn_exp2f(x)
#else
  #define EXP2(x) exp2f(x)
#endif

__device__ __forceinline__ u16 f2b(float f) {
  return __builtin_bit_cast(u16, __float2bfloat16(f));
}
__device__ __forceinline__ float b2f(u16 h) {
  union { uint32_t u; float f; } v; v.u = ((uint32_t)h) << 16;
  return v.f;
}
__device__ __forceinline__ uint32_t pack2(float a, float b) {
  return (uint32_t)f2b(a) | ((uint32_t)f2b(b) << 16);
}
__device__ __forceinline__ float max3f(float a, float b, float c) {
  return fmaxf(fmaxf(a, b), c);
}
__device__ __forceinline__ f4_t mfma16(bf8_t a, bf8_t b, f4_t c) {
  return __builtin_amdgcn_mfma_f32_16x16x32_bf16(a, b, c, 0, 0, 0);
}
__device__ __forceinline__ f16v mfma32(bf8_t a, bf8_t b, f16v c) {
  return __builtin_amdgcn_mfma_f32_32x32x16_bf16(a, b, c, 0, 0, 0);
}
// Compiler-modeled permlane32 swap. SAFE ONLY ON DISTINCT VALUES (R3/R6).
__device__ __forceinline__ void pl32swap(uint32_t &a, uint32_t &b) {
  u32x2 r = __builtin_amdgcn_permlane32_swap(a, b, false, false);
  a = r[0];
  b = r[1];
}

// ---------------------------------------------------------------------------
// Kernel 1: fused projections — R19/R21-verified best (unchanged).
// ---------------------------------------------------------------------------
__global__ __launch_bounds__(256) void proj_kernel(
    const float* __restrict__ x,
    const float* __restrict__ tw, const float* __restrict__ tb,
    const float* __restrict__ pw, const float* __restrict__ pb,
    const float* __restrict__ gw, const float* __restrict__ gb,
    u16* __restrict__ theta_h, u16* __restrict__ phi_h, u16* __restrict__ gt_h) {
  __shared__ __align__(16) u16 smem[12800];   // xT[64][136] / yO[64][200]
  const int blk = blockIdx.x;
  const int b  = blk >> 6;
  const int n0 = (blk & 63) << 6;
  const int tid = threadIdx.x;

  #pragma unroll
  for (int i = 0; i < 8; ++i) {
    int idx = tid + i * 256;
    int px = (idx & 15) * 4;
    int c  = idx >> 4;
    int m  = px >> 2;
    float4 v = *(const float4*)(x + ((size_t)b * CH + c) * N_PIX + n0 + px);
    int base = px * 136 + ((((c >> 3) ^ m) & 15) << 3) + (c & 7);
    smem[base]       = f2b(v.x);
    smem[base + 136] = f2b(v.y);
    smem[base + 272] = f2b(v.z);
    smem[base + 408] = f2b(v.w);
  }
  __syncthreads();

  const int lane = tid & 63;
  const int w    = tid >> 6;
  const int l4   = lane >> 4, l15 = lane & 15;

  bf8_t bw[3][4];
  float bias[3];
  #pragma unroll
  for (int nt = 0; nt < 3; ++nt) {
    int op = 16 * (3 * w + nt) + l15;
    const float* wrow; float bv; float scl;
    if (op < 64)       { wrow = tw + op * CH;          bv = tb[op];        scl = L2E; }
    else if (op < 128) { wrow = pw + (op - 64) * CH;   bv = pb[op - 64];   scl = 1.f; }
    else               { wrow = gw + (op - 128) * CH;  bv = gb[op - 128];  scl = 1.f; }
    bias[nt] = bv * scl;
    #pragma unroll
    for (int ks = 0; ks < 4; ++ks) {
      const float* p = wrow + 32 * ks + l4 * 8;
      bf8_t v;
      #pragma unroll
      for (int j = 0; j < 8; ++j) v[j] = (short)f2b(p[j] * scl);
      bw[nt][ks] = v;
    }
  }

  f4_t acc[4][3];
  #pragma unroll
  for (int mt = 0; mt < 4; ++mt)
    #pragma unroll
    for (int nt = 0; nt < 3; ++nt) acc[mt][nt] = (f4_t){0.f, 0.f, 0.f, 0.f};

  #pragma unroll
  for (int mt = 0; mt < 4; ++mt) {
    int row = l15 + 16 * mt;
    #pragma unroll
    for (int ks = 0; ks < 4; ++ks) {
      int ch = ((4 * ks + l4) ^ (row >> 2)) & 15;
      bf8_t a = *(const bf8_t*)&smem[row * 136 + (ch << 3)];
      #pragma unroll
      for (int nt = 0; nt < 3; ++nt)
        acc[mt][nt] = mfma16(a, bw[nt][ks], acc[mt][nt]);
    }
  }
  __syncthreads();

  #pragma unroll
  for (int nt = 0; nt < 3; ++nt) {
    int op = 16 * (3 * w + nt) + l15;
    #pragma unroll
    for (int mt = 0; mt < 4; ++mt) {
      #pragma unroll
      for (int r = 0; r < 4; ++r) {
        int ql = 16 * mt + l4 * 4 + r;
        smem[ql * 200 + op] = f2b(acc[mt][nt][r] + bias[nt]);
      }
    }
  }
  __syncthreads();

  #pragma unroll
  for (int i = 0; i < 4; ++i) {
    int idx = tid + i * 256;
    int q  = idx >> 4;
    int ch = idx & 15;
    uint4 v = *(const uint4*)&smem[q * 200 + ch * 8];
    if (ch < 8)
      *(uint4*)(theta_h + ((size_t)b * N_PIX + n0 + q) * DD + ch * 8) = v;
    else
      *(uint4*)(phi_h + ((size_t)b * N_PIX + n0 + q) * DD + (ch - 8) * 8) = v;
  }
  #pragma unroll
  for (int i = 0; i < 2; ++i) {
    int idx = tid + i * 256;
    int o = idx >> 3;
    int j = idx & 7;
    uint4 v;
    uint32_t* vp = (uint32_t*)&v;
    #pragma unroll
    for (int k = 0; k < 4; ++k) {
      u16 lo = smem[(8 * j + 2 * k) * 200 + 128 + o];
      u16 hi = smem[(8 * j + 2 * k + 1) * 200 + 128 + o];
      vp[k] = (uint32_t)lo | ((uint32_t)hi << 16);
    }
    *(uint4*)(gt_h + ((size_t)b * DD + o) * N_PIX + n0 + 8 * j) = v;
  }
}

// ---------------------------------------------------------------------------
// Kernel 2: flash attention — 128 q per block via 16 WAVES (1024 threads),
// 256 blocks. Combines R22's halved staging traffic (each phi/gt byte staged
// once per 128 q) with R21's TLP (16 waves/CU): the second q-set lives in
// waves 8-15 (single-stream per-wave code = R21-verified, low VGPR) instead
// of extra registers per wave (R22, occupancy-limited). Staging work per
// thread also halves (2 x 16B chunks). Epilogue = R21 merge+outproj, run
// sequentially per q-set.
// ---------------------------------------------------------------------------
__global__ __launch_bounds__(1024, 4) void attn_kernel(
    const u16* __restrict__ theta_h, const u16* __restrict__ phi_h,
    const u16* __restrict__ gt_h,
    const float* __restrict__ ow, const float* __restrict__ ob,
    const float* __restrict__ x, float* __restrict__ out) {
  __shared__ __align__(16) u16 smem[32768];   // 64 KiB

  const int bid = blockIdx.x;                  // 256 blocks, 256 % 8 == 0
  const int lb  = (bid & 7) * 32 + (bid >> 3); // XCD swizzle: batch per XCD
  const int b   = lb >> 5;
  const int q0  = (lb & 31) << 7;              // 128-q tile
  const int tid = threadIdx.x;
  const int l   = tid & 63;
  const int w   = tid >> 6;    // 0..15
  const int qs  = w >> 3;      // q-set (0: q0.., 1: q0+64..)
  const int wq  = w & 7;
  const int qg  = wq & 1;      // q-group (32 q within the set)
  const int mh  = wq >> 1;     // m-slice (32 of each 128-key tile)
  const int l31 = l & 31;
  const int hi  = l >> 5;

  // theta B-fragments: theta[q = q0+64qs+32qg+l31][k = 16kk+8hi..]
  bf8_t th[4];
  {
    const u16* trow =
        theta_h + ((size_t)b * N_PIX + q0 + 64 * qs + 32 * qg + l31) * DD;
    #pragma unroll
    for (int kk = 0; kk < 4; ++kk)
      th[kk] = *(const bf8_t*)(trow + 16 * kk + 8 * hi);
  }

  const bf8_t onesA = __builtin_bit_cast(bf8_t,
      (u32x4){0x3F803F80u, 0x3F803F80u, 0x3F803F80u, 0x3F803F80u});

  f16v yacc[2];
  #pragma unroll
  for (int ot = 0; ot < 2; ++ot)
    #pragma unroll
    for (int r = 0; r < 16; ++r) yacc[ot][r] = 0.f;
  f16v y2;                       // row-sum accumulator; only y2[0] is consumed
  #pragma unroll
  for (int r = 0; r < 16; ++r) y2[r] = 0.f;
  float m_ = -1e30f;

  // ---- staging: 1024 threads x (1 phi chunk + 1 gt chunk) of 16B ---------
  const int pr  = tid >> 3, pc = tid & 7;      // phi: 128 rows x 8 chunks
  const int go  = tid >> 4, gc = tid & 15;     // gt:  64 rows x 16 chunks
  const u16* phA = phi_h + ((size_t)b * N_PIX + pr) * DD + pc * 8;
  const u16* gtA = gt_h + ((size_t)b * DD + go) * N_PIX + gc * 8;
  const int pO0 = pr * 64 + ((pc ^ (pr & 7)) << 3);
  const int gO0 = 8192 + go * 128 + ((gc ^ (go & 7)) << 3);

  uint4 v0, v1;
  #define LOADS(kb_) do {                                              \
    v0 = *(const uint4*)(phA + (size_t)(kb_) * 8192);                  \
    v1 = *(const uint4*)(gtA + (size_t)(kb_) * 128);                   \
  } while (0)
  #define WRITES(buf_) do {                                            \
    u16* base_ = smem + (buf_) * 16384;                                \
    *(uint4*)(base_ + pO0) = v0;                                       \
    *(uint4*)(base_ + gO0) = v1;                                       \
  } while (0)

  LOADS(0); WRITES(0);
  __syncthreads();

  const int prow  = 32 * mh + l31;
  const int pbase = prow * 64;
  const int pkey  = prow & 7;

  #pragma unroll 2
  for (int t = 0; t < NT; ++t) {
    const int cur = t & 1;
    if (t < NT - 1) LOADS(t + 1);
    const u16* pb = smem + cur * 16384;
    const u16* gb = pb + 8192;

    // ---- QK^T (swapped): ST[m][q], 4 x mfma32 over K=64 ------------------
    f16v st;
    #pragma unroll
    for (int r = 0; r < 16; ++r) st[r] = 0.f;
    __builtin_amdgcn_s_setprio(1);
    #pragma unroll
    for (int kk = 0; kk < 4; ++kk) {
      bf8_t a = *(const bf8_t*)(pb + pbase + (((2 * kk + hi) ^ pkey) << 3));
      st = mfma32(a, th[kk], st);
    }
    __builtin_amdgcn_s_setprio(0);

    // ---- max: max3 tree + cross-half shfl (verified) ---------------------
    float t0 = max3f(st[0],  st[1],  st[2]);
    float t1 = max3f(st[3],  st[4],  st[5]);
    float t2 = max3f(st[6],  st[7],  st[8]);
    float t3 = max3f(st[9],  st[10], st[11]);
    float t4 = max3f(st[12], st[13], st[14]);
    float pmax = fmaxf(max3f(t0, t1, t2), max3f(t3, t4, st[15]));
    pmax = fmaxf(pmax, __shfl_xor(pmax, 32));

    // ---- defer-max (T13) --------------------------------------------------
    if (!__all(pmax <= m_ + 8.f)) {
      float mn = fmaxf(m_, pmax);
      float sc = EXP2(m_ - mn);
      m_ = mn;
      y2[0] *= sc;
      #pragma unroll
      for (int ot = 0; ot < 2; ++ot)
        #pragma unroll
        for (int r = 0; r < 16; ++r) yacc[ot][r] *= sc;
    }

    // ---- P = 2^(st - m) ----------------------------------------------------
    #pragma unroll
    for (int r = 0; r < 16; ++r) st[r] = EXP2(st[r] - m_);

    // ---- P -> PV B-fragments (pack + permlane swap, distinct) -------------
    uint32_t c0 = pack2(st[0],  st[1]),  c1 = pack2(st[2],  st[3]);
    uint32_t c2 = pack2(st[4],  st[5]),  c3 = pack2(st[6],  st[7]);
    uint32_t c4 = pack2(st[8],  st[9]),  c5 = pack2(st[10], st[11]);
    uint32_t c6 = pack2(st[12], st[13]), c7 = pack2(st[14], st[15]);
    pl32swap(c0, c2); pl32swap(c1, c3);
    pl32swap(c4, c6); pl32swap(c5, c7);
    bf8_t pf0 = __builtin_bit_cast(bf8_t, (u32x4){c0, c1, c2, c3});
    bf8_t pf1 = __builtin_bit_cast(bf8_t, (u32x4){c4, c5, c6, c7});

    // ---- PV + row-sum ------------------------------------------------------
    __builtin_amdgcn_s_setprio(1);
    y2 = mfma32(onesA, pf0, y2);
    y2 = mfma32(onesA, pf1, y2);
    #pragma unroll
    for (int ot = 0; ot < 2; ++ot) {
      int orow  = 32 * ot + l31;
      int obase = orow * 128;
      int okey  = orow & 7;
      bf8_t g0 = *(const bf8_t*)(gb + obase + ((((mh << 2) + hi)     ^ okey) << 3));
      yacc[ot] = mfma32(g0, pf0, yacc[ot]);
      bf8_t g1 = *(const bf8_t*)(gb + obase + ((((mh << 2) + 2 + hi) ^ okey) << 3));
      yacc[ot] = mfma32(g1, pf1, yacc[ot]);
    }
    __builtin_amdgcn_s_setprio(0);

    if (t < NT - 1) WRITES(cur ^ 1);
    __syncthreads();
  }
  #undef LOADS
  #undef WRITES

  float l_ = y2[0];

  float* ml = (float*)(smem + 16384);
  u16* y_lds = smem + 17408;   // [64 q][72 pitch] bf16

  // ================= sequential epilogue, one pass per q-set ==============
  #pragma unroll
  for (int s = 0; s < 2; ++s) {
    if (qs == s) {
      #pragma unroll
      for (int ot = 0; ot < 2; ++ot)
        #pragma unroll
        for (int r = 0; r < 16; ++r) {
          int o = 32 * ot + (r & 3) + 8 * (r >> 2) + 4 * hi;
          smem[(((qg * 4 + mh) * 64 + o) << 5) + l31] = f2b(yacc[ot][r]);
        }
      if (hi == 0) {
        ml[(qg * 4 + mh) * 64 + l31]      = m_;
        ml[(qg * 4 + mh) * 64 + 32 + l31] = l_;
      }
    }
    __syncthreads();

    if (tid < 512) {
      const int qg2 = tid >> 8;
      const int rem = tid & 255;
      const int qq  = rem & 31;
      const int og  = rem >> 5;
      float mi[4], li[4];
      #pragma unroll
      for (int i = 0; i < 4; ++i) {
        mi[i] = ml[(qg2 * 4 + i) * 64 + qq];
        li[i] = ml[(qg2 * 4 + i) * 64 + 32 + qq];
      }
      float M = fmaxf(fmaxf(mi[0], mi[1]), fmaxf(mi[2], mi[3]));
      float e[4], L = 0.f;
      #pragma unroll
      for (int i = 0; i < 4; ++i) { e[i] = EXP2(mi[i] - M); L += li[i] * e[i]; }
      float invL = 1.0f / L;
      float acc[8];
      #pragma unroll
      for (int oo = 0; oo < 8; ++oo) {
        int o = og * 8 + oo;
        float a = 0.f;
        #pragma unroll
        for (int i = 0; i < 4; ++i)
          a += b2f(smem[(((qg2 * 4 + i) * 64 + o) << 5) + qq]) * e[i];
        acc[oo] = a * invL;
      }
      uint4 ov;
      ov.x = pack2(acc[0], acc[1]);
      ov.y = pack2(acc[2], acc[3]);
      ov.z = pack2(acc[4], acc[5]);
      ov.w = pack2(acc[6], acc[7]);
      *(uint4*)(y_lds + (32 * qg2 + qq) * 72 + og * 8) = ov;
    }
    __syncthreads();

    if (w < 8) {
      const int ct = w & 3;
      const int qt = w >> 2;
      f16v oacc;
      #pragma unroll
      for (int r = 0; r < 16; ++r) oacc[r] = 0.f;
      #pragma unroll
      for (int kk = 0; kk < 4; ++kk) {
        const float* wp = ow + (size_t)(32 * ct + l31) * DD + 16 * kk + 8 * hi;
        bf8_t av;
        #pragma unroll
        for (int j = 0; j < 8; ++j) av[j] = (short)f2b(wp[j]);
        bf8_t bv = *(const bf8_t*)(y_lds + (32 * qt + l31) * 72 + 16 * kk + 8 * hi);
        oacc = mfma32(av, bv, oacc);
      }
      #pragma unroll
      for (int r = 0; r < 16; ++r) {
        int c = 32 * ct + (r & 3) + 8 * (r >> 2) + 4 * hi;
        size_t gi = ((size_t)b * CH + c) * N_PIX + q0 + 64 * s + 32 * qt + l31;
        out[gi] = oacc[r] + ob[c] + x[gi];
      }
    }
    __syncthreads();
  }
}

extern "C" void kernel_launch(void* const* d_in, const int* in_sizes, int n_in,
                              void* d_out, int out_size, void* d_ws, size_t ws_size,
                              hipStream_t stream) {
  const float* x  = (const float*)d_in[0];
  const float* tw = (const float*)d_in[1];
  const float* tb = (const float*)d_in[2];
  const float* pw = (const float*)d_in[3];
  const float* pb = (const float*)d_in[4];
  const float* gw = (const float*)d_in[5];
  const float* gb = (const float*)d_in[6];
  const float* ow = (const float*)d_in[7];
  const float* ob = (const float*)d_in[8];
  float* out = (float*)d_out;

  const size_t sz = (size_t)NBATCH * N_PIX * DD;   // elems per bf16 tensor
  u16* theta_h = (u16*)d_ws;
  u16* phi_h   = theta_h + sz;
  u16* gt_h    = phi_h + sz;

  proj_kernel<<<512, 256, 0, stream>>>(x, tw, tb, pw, pb, gw, gb,
                                       theta_h, phi_h, gt_h);
  attn_kernel<<<256, 1024, 0, stream>>>(theta_h, phi_h, gt_h, ow, ob, x, out);
}

// Round 24
// 77.381 us; speedup vs baseline: 1.0230x; 1.0230x over previous
//
#include <hip/hip_runtime.h>
#include <hip/hip_bf16.h>
#include <cstdint>
#include <cmath>

#define N_PIX 4096
#define CH    128
#define DD    64
#define NBATCH 8
#define NT    32    // 4096 / 128 key-tiles

typedef unsigned short u16;
typedef __attribute__((ext_vector_type(8))) short bf8_t;
typedef __attribute__((ext_vector_type(4))) float f4_t;
typedef __attribute__((ext_vector_type(16))) float f16v;
typedef uint32_t u32x4 __attribute__((ext_vector_type(4)));
typedef uint32_t u32x2 __attribute__((ext_vector_type(2)));

#define L2E 1.44269504088896340736f

#if __has_builtin(__builtin_amdgcn_exp2f)
  #define EXP2(x) __builtin_amdgcn_exp2f(x)
#else
  #define EXP2(x) exp2f(x)
#endif

__device__ __forceinline__ u16 f2b(float f) {
  return __builtin_bit_cast(u16, __float2bfloat16(f));
}
__device__ __forceinline__ float b2f(u16 h) {
  union { uint32_t u; float f; } v; v.u = ((uint32_t)h) << 16;
  return v.f;
}
__device__ __forceinline__ uint32_t pack2(float a, float b) {
  return (uint32_t)f2b(a) | ((uint32_t)f2b(b) << 16);
}
__device__ __forceinline__ float max3f(float a, float b, float c) {
  return fmaxf(fmaxf(a, b), c);
}
__device__ __forceinline__ f4_t mfma16(bf8_t a, bf8_t b, f4_t c) {
  return __builtin_amdgcn_mfma_f32_16x16x32_bf16(a, b, c, 0, 0, 0);
}
__device__ __forceinline__ f16v mfma32(bf8_t a, bf8_t b, f16v c) {
  return __builtin_amdgcn_mfma_f32_32x32x16_bf16(a, b, c, 0, 0, 0);
}
// Compiler-modeled permlane32 swap. SAFE ONLY ON DISTINCT VALUES (R3/R6).
__device__ __forceinline__ void pl32swap(uint32_t &a, uint32_t &b) {
  u32x2 r = __builtin_amdgcn_permlane32_swap(a, b, false, false);
  a = r[0];
  b = r[1];
}

// ---------------------------------------------------------------------------
// Kernel 1: fused projections — R19/R21-verified best (unchanged).
// ---------------------------------------------------------------------------
__global__ __launch_bounds__(256) void proj_kernel(
    const float* __restrict__ x,
    const float* __restrict__ tw, const float* __restrict__ tb,
    const float* __restrict__ pw, const float* __restrict__ pb,
    const float* __restrict__ gw, const float* __restrict__ gb,
    u16* __restrict__ theta_h, u16* __restrict__ phi_h, u16* __restrict__ gt_h) {
  __shared__ __align__(16) u16 smem[12800];   // xT[64][136] / yO[64][200]
  const int blk = blockIdx.x;
  const int b  = blk >> 6;
  const int n0 = (blk & 63) << 6;
  const int tid = threadIdx.x;

  #pragma unroll
  for (int i = 0; i < 8; ++i) {
    int idx = tid + i * 256;
    int px = (idx & 15) * 4;
    int c  = idx >> 4;
    int m  = px >> 2;
    float4 v = *(const float4*)(x + ((size_t)b * CH + c) * N_PIX + n0 + px);
    int base = px * 136 + ((((c >> 3) ^ m) & 15) << 3) + (c & 7);
    smem[base]       = f2b(v.x);
    smem[base + 136] = f2b(v.y);
    smem[base + 272] = f2b(v.z);
    smem[base + 408] = f2b(v.w);
  }
  __syncthreads();

  const int lane = tid & 63;
  const int w    = tid >> 6;
  const int l4   = lane >> 4, l15 = lane & 15;

  bf8_t bw[3][4];
  float bias[3];
  #pragma unroll
  for (int nt = 0; nt < 3; ++nt) {
    int op = 16 * (3 * w + nt) + l15;
    const float* wrow; float bv; float scl;
    if (op < 64)       { wrow = tw + op * CH;          bv = tb[op];        scl = L2E; }
    else if (op < 128) { wrow = pw + (op - 64) * CH;   bv = pb[op - 64];   scl = 1.f; }
    else               { wrow = gw + (op - 128) * CH;  bv = gb[op - 128];  scl = 1.f; }
    bias[nt] = bv * scl;
    #pragma unroll
    for (int ks = 0; ks < 4; ++ks) {
      const float* p = wrow + 32 * ks + l4 * 8;
      bf8_t v;
      #pragma unroll
      for (int j = 0; j < 8; ++j) v[j] = (short)f2b(p[j] * scl);
      bw[nt][ks] = v;
    }
  }

  f4_t acc[4][3];
  #pragma unroll
  for (int mt = 0; mt < 4; ++mt)
    #pragma unroll
    for (int nt = 0; nt < 3; ++nt) acc[mt][nt] = (f4_t){0.f, 0.f, 0.f, 0.f};

  #pragma unroll
  for (int mt = 0; mt < 4; ++mt) {
    int row = l15 + 16 * mt;
    #pragma unroll
    for (int ks = 0; ks < 4; ++ks) {
      int ch = ((4 * ks + l4) ^ (row >> 2)) & 15;
      bf8_t a = *(const bf8_t*)&smem[row * 136 + (ch << 3)];
      #pragma unroll
      for (int nt = 0; nt < 3; ++nt)
        acc[mt][nt] = mfma16(a, bw[nt][ks], acc[mt][nt]);
    }
  }
  __syncthreads();

  #pragma unroll
  for (int nt = 0; nt < 3; ++nt) {
    int op = 16 * (3 * w + nt) + l15;
    #pragma unroll
    for (int mt = 0; mt < 4; ++mt) {
      #pragma unroll
      for (int r = 0; r < 4; ++r) {
        int ql = 16 * mt + l4 * 4 + r;
        smem[ql * 200 + op] = f2b(acc[mt][nt][r] + bias[nt]);
      }
    }
  }
  __syncthreads();

  #pragma unroll
  for (int i = 0; i < 4; ++i) {
    int idx = tid + i * 256;
    int q  = idx >> 4;
    int ch = idx & 15;
    uint4 v = *(const uint4*)&smem[q * 200 + ch * 8];
    if (ch < 8)
      *(uint4*)(theta_h + ((size_t)b * N_PIX + n0 + q) * DD + ch * 8) = v;
    else
      *(uint4*)(phi_h + ((size_t)b * N_PIX + n0 + q) * DD + (ch - 8) * 8) = v;
  }
  #pragma unroll
  for (int i = 0; i < 2; ++i) {
    int idx = tid + i * 256;
    int o = idx >> 3;
    int j = idx & 7;
    uint4 v;
    uint32_t* vp = (uint32_t*)&v;
    #pragma unroll
    for (int k = 0; k < 4; ++k) {
      u16 lo = smem[(8 * j + 2 * k) * 200 + 128 + o];
      u16 hi = smem[(8 * j + 2 * k + 1) * 200 + 128 + o];
      vp[k] = (uint32_t)lo | ((uint32_t)hi << 16);
    }
    *(uint4*)(gt_h + ((size_t)b * DD + o) * N_PIX + n0 + 8 * j) = v;
  }
}

// ---------------------------------------------------------------------------
// Kernel 2: flash attention, TWO q-tiles per block (128 q, 256 blocks) —
// R22-verified best (77.85µs total). Streams A (q0..q0+63) and B (+64..+128)
// share ALL staged data: the QK phi A-fragment and the PV g-fragments feed
// two MFMAs each. Staging traffic, barriers, and LDS reads per unit work
// halve vs 64q blocks (measured: conflicts 4.19M -> 2.10M). Row-sum via
// own-half VALU tree + one end shfl. Fused out-projection epilogue per set.
// ---------------------------------------------------------------------------
__global__ __launch_bounds__(512, 2) void attn_kernel(
    const u16* __restrict__ theta_h, const u16* __restrict__ phi_h,
    const u16* __restrict__ gt_h,
    const float* __restrict__ ow, const float* __restrict__ ob,
    const float* __restrict__ x, float* __restrict__ out) {
  __shared__ __align__(16) u16 smem[32768];   // 64 KiB

  const int bid = blockIdx.x;                  // 256 blocks, 256 % 8 == 0
  const int lb  = (bid & 7) * 32 + (bid >> 3); // XCD swizzle: batch per XCD
  const int b   = lb >> 5;
  const int q0  = (lb & 31) << 7;              // 128-q tile
  const int tid = threadIdx.x;
  const int l   = tid & 63;
  const int w   = tid >> 6;
  const int qg  = w & 1;    // q-group (32 q within a 64-q set)
  const int mh  = w >> 1;   // m-slice (32 of each 128-key tile)
  const int l31 = l & 31;
  const int hi  = l >> 5;

  // theta B-fragments for both q-sets
  bf8_t thA[4], thB[4];
  {
    const u16* trowA = theta_h + ((size_t)b * N_PIX + q0 + 32 * qg + l31) * DD;
    const u16* trowB = trowA + 64 * DD;
    #pragma unroll
    for (int kk = 0; kk < 4; ++kk) {
      thA[kk] = *(const bf8_t*)(trowA + 16 * kk + 8 * hi);
      thB[kk] = *(const bf8_t*)(trowB + 16 * kk + 8 * hi);
    }
  }

  f16v yaccA[2], yaccB[2];
  #pragma unroll
  for (int ot = 0; ot < 2; ++ot)
    #pragma unroll
    for (int r = 0; r < 16; ++r) { yaccA[ot][r] = 0.f; yaccB[ot][r] = 0.f; }
  float mA = -1e30f, lA = 0.f;   // l = own-half sum; cross-half after loop
  float mB = -1e30f, lB = 0.f;

  // ---- staging addresses (identical to verified; q-independent) ----------
  const int pr  = tid >> 3, pc = tid & 7;
  const int go  = tid >> 4, gc = tid & 15;
  const u16* phA = phi_h + ((size_t)b * N_PIX + pr) * DD + pc * 8;
  const u16* gtA = gt_h + ((size_t)b * DD + go) * N_PIX + gc * 8;
  const int pO0 = pr * 64 + ((pc ^ (pr & 7)) << 3);
  const int pO1 = pO0 + 4096;
  const int gO0 = 8192 + go * 128 + ((gc ^ (go & 7)) << 3);
  const int gO1 = gO0 + 4096;

  uint4 v0, v1, v2, v3;
  #define LOADS(kb_) do {                                              \
    v0 = *(const uint4*)(phA + (size_t)(kb_) * 8192);                  \
    v1 = *(const uint4*)(phA + (size_t)(kb_) * 8192 + 4096);           \
    v2 = *(const uint4*)(gtA + (size_t)(kb_) * 128);                   \
    v3 = *(const uint4*)(gtA + (size_t)(kb_) * 128 + 32 * (size_t)N_PIX); \
  } while (0)
  #define WRITES(buf_) do {                                            \
    u16* base_ = smem + (buf_) * 16384;                                \
    *(uint4*)(base_ + pO0) = v0;                                       \
    *(uint4*)(base_ + pO1) = v1;                                       \
    *(uint4*)(base_ + gO0) = v2;                                       \
    *(uint4*)(base_ + gO1) = v3;                                       \
  } while (0)

  LOADS(0); WRITES(0);
  __syncthreads();

  const int prow  = 32 * mh + l31;
  const int pbase = prow * 64;
  const int pkey  = prow & 7;

  for (int t = 0; t < NT; ++t) {
    const int cur = t & 1;
    if (t < NT - 1) LOADS(t + 1);
    const u16* pb = smem + cur * 16384;
    const u16* gb = pb + 8192;

    // ---- QK^T both streams: shared phi A-fragment -----------------------
    f16v stA, stB;
    #pragma unroll
    for (int r = 0; r < 16; ++r) { stA[r] = 0.f; stB[r] = 0.f; }
    __builtin_amdgcn_s_setprio(1);
    #pragma unroll
    for (int kk = 0; kk < 4; ++kk) {
      bf8_t a = *(const bf8_t*)(pb + pbase + (((2 * kk + hi) ^ pkey) << 3));
      stA = mfma32(a, thA[kk], stA);
      stB = mfma32(a, thB[kk], stB);
    }
    __builtin_amdgcn_s_setprio(0);

    // ---- softmax A -------------------------------------------------------
    {
      float t0 = max3f(stA[0],  stA[1],  stA[2]);
      float t1 = max3f(stA[3],  stA[4],  stA[5]);
      float t2 = max3f(stA[6],  stA[7],  stA[8]);
      float t3 = max3f(stA[9],  stA[10], stA[11]);
      float t4 = max3f(stA[12], stA[13], stA[14]);
      float pmax = fmaxf(max3f(t0, t1, t2), max3f(t3, t4, stA[15]));
      pmax = fmaxf(pmax, __shfl_xor(pmax, 32));
      if (!__all(pmax <= mA + 8.f)) {
        float mn = fmaxf(mA, pmax);
        float sc = EXP2(mA - mn);
        mA = mn;
        lA *= sc;
        #pragma unroll
        for (int ot = 0; ot < 2; ++ot)
          #pragma unroll
          for (int r = 0; r < 16; ++r) yaccA[ot][r] *= sc;
      }
      #pragma unroll
      for (int r = 0; r < 16; ++r) stA[r] = EXP2(stA[r] - mA);
      float s0 = stA[0] + stA[1],   s1 = stA[2] + stA[3];
      float s2 = stA[4] + stA[5],   s3 = stA[6] + stA[7];
      float s4 = stA[8] + stA[9],   s5 = stA[10] + stA[11];
      float s6 = stA[12] + stA[13], s7 = stA[14] + stA[15];
      lA += ((s0 + s1) + (s2 + s3)) + ((s4 + s5) + (s6 + s7));
    }
    uint32_t a0 = pack2(stA[0],  stA[1]),  a1 = pack2(stA[2],  stA[3]);
    uint32_t a2 = pack2(stA[4],  stA[5]),  a3 = pack2(stA[6],  stA[7]);
    uint32_t a4 = pack2(stA[8],  stA[9]),  a5 = pack2(stA[10], stA[11]);
    uint32_t a6 = pack2(stA[12], stA[13]), a7 = pack2(stA[14], stA[15]);
    pl32swap(a0, a2); pl32swap(a1, a3);
    pl32swap(a4, a6); pl32swap(a5, a7);
    bf8_t pfA0 = __builtin_bit_cast(bf8_t, (u32x4){a0, a1, a2, a3});
    bf8_t pfA1 = __builtin_bit_cast(bf8_t, (u32x4){a4, a5, a6, a7});

    // ---- softmax B -------------------------------------------------------
    {
      float t0 = max3f(stB[0],  stB[1],  stB[2]);
      float t1 = max3f(stB[3],  stB[4],  stB[5]);
      float t2 = max3f(stB[6],  stB[7],  stB[8]);
      float t3 = max3f(stB[9],  stB[10], stB[11]);
      float t4 = max3f(stB[12], stB[13], stB[14]);
      float pmax = fmaxf(max3f(t0, t1, t2), max3f(t3, t4, stB[15]));
      pmax = fmaxf(pmax, __shfl_xor(pmax, 32));
      if (!__all(pmax <= mB + 8.f)) {
        float mn = fmaxf(mB, pmax);
        float sc = EXP2(mB - mn);
        mB = mn;
        lB *= sc;
        #pragma unroll
        for (int ot = 0; ot < 2; ++ot)
          #pragma unroll
          for (int r = 0; r < 16; ++r) yaccB[ot][r] *= sc;
      }
      #pragma unroll
      for (int r = 0; r < 16; ++r) stB[r] = EXP2(stB[r] - mB);
      float s0 = stB[0] + stB[1],   s1 = stB[2] + stB[3];
      float s2 = stB[4] + stB[5],   s3 = stB[6] + stB[7];
      float s4 = stB[8] + stB[9],   s5 = stB[10] + stB[11];
      float s6 = stB[12] + stB[13], s7 = stB[14] + stB[15];
      lB += ((s0 + s1) + (s2 + s3)) + ((s4 + s5) + (s6 + s7));
    }
    uint32_t b0 = pack2(stB[0],  stB[1]),  b1 = pack2(stB[2],  stB[3]);
    uint32_t b2 = pack2(stB[4],  stB[5]),  b3 = pack2(stB[6],  stB[7]);
    uint32_t b4 = pack2(stB[8],  stB[9]),  b5 = pack2(stB[10], stB[11]);
    uint32_t b6 = pack2(stB[12], stB[13]), b7 = pack2(stB[14], stB[15]);
    pl32swap(b0, b2); pl32swap(b1, b3);
    pl32swap(b4, b6); pl32swap(b5, b7);
    bf8_t pfB0 = __builtin_bit_cast(bf8_t, (u32x4){b0, b1, b2, b3});
    bf8_t pfB1 = __builtin_bit_cast(bf8_t, (u32x4){b4, b5, b6, b7});

    // ---- PV both streams: shared g fragments -----------------------------
    __builtin_amdgcn_s_setprio(1);
    #pragma unroll
    for (int ot = 0; ot < 2; ++ot) {
      int orow  = 32 * ot + l31;
      int obase = orow * 128;
      int okey  = orow & 7;
      bf8_t g0 = *(const bf8_t*)(gb + obase + ((((mh << 2) + hi)     ^ okey) << 3));
      yaccA[ot] = mfma32(g0, pfA0, yaccA[ot]);
      yaccB[ot] = mfma32(g0, pfB0, yaccB[ot]);
      bf8_t g1 = *(const bf8_t*)(gb + obase + ((((mh << 2) + 2 + hi) ^ okey) << 3));
      yaccA[ot] = mfma32(g1, pfA1, yaccA[ot]);
      yaccB[ot] = mfma32(g1, pfB1, yaccB[ot]);
    }
    __builtin_amdgcn_s_setprio(0);

    if (t < NT - 1) WRITES(cur ^ 1);
    __syncthreads();
  }
  #undef LOADS
  #undef WRITES

  // deferred cross-half sums (pair has identical rescale history)
  lA += __shfl_xor(lA, 32);
  lB += __shfl_xor(lB, 32);

  float* ml = (float*)(smem + 16384);
  u16* y_lds = smem + 17408;   // [64 q][72 pitch] bf16

  // ================= epilogue pass A (q0 .. q0+63) ========================
  #pragma unroll
  for (int ot = 0; ot < 2; ++ot)
    #pragma unroll
    for (int r = 0; r < 16; ++r) {
      int o = 32 * ot + (r & 3) + 8 * (r >> 2) + 4 * hi;
      smem[(((qg * 4 + mh) * 64 + o) << 5) + l31] = f2b(yaccA[ot][r]);
    }
  if (hi == 0) {
    ml[(qg * 4 + mh) * 64 + l31]      = mA;
    ml[(qg * 4 + mh) * 64 + 32 + l31] = lA;
  }
  __syncthreads();
  {
    const int qg2 = tid >> 8;
    const int rem = tid & 255;
    const int qq  = rem & 31;
    const int og  = rem >> 5;
    float mi[4], li[4];
    #pragma unroll
    for (int i = 0; i < 4; ++i) {
      mi[i] = ml[(qg2 * 4 + i) * 64 + qq];
      li[i] = ml[(qg2 * 4 + i) * 64 + 32 + qq];
    }
    float M = fmaxf(fmaxf(mi[0], mi[1]), fmaxf(mi[2], mi[3]));
    float e[4], L = 0.f;
    #pragma unroll
    for (int i = 0; i < 4; ++i) { e[i] = EXP2(mi[i] - M); L += li[i] * e[i]; }
    float invL = 1.0f / L;
    float acc[8];
    #pragma unroll
    for (int oo = 0; oo < 8; ++oo) {
      int o = og * 8 + oo;
      float a = 0.f;
      #pragma unroll
      for (int i = 0; i < 4; ++i)
        a += b2f(smem[(((qg2 * 4 + i) * 64 + o) << 5) + qq]) * e[i];
      acc[oo] = a * invL;
    }
    uint4 ov;
    ov.x = pack2(acc[0], acc[1]);
    ov.y = pack2(acc[2], acc[3]);
    ov.z = pack2(acc[4], acc[5]);
    ov.w = pack2(acc[6], acc[7]);
    *(uint4*)(y_lds + (32 * qg2 + qq) * 72 + og * 8) = ov;
  }
  __syncthreads();
  {
    const int ct = w & 3;
    const int qt = w >> 2;
    f16v oacc;
    #pragma unroll
    for (int r = 0; r < 16; ++r) oacc[r] = 0.f;
    #pragma unroll
    for (int kk = 0; kk < 4; ++kk) {
      const float* wp = ow + (size_t)(32 * ct + l31) * DD + 16 * kk + 8 * hi;
      bf8_t av;
      #pragma unroll
      for (int j = 0; j < 8; ++j) av[j] = (short)f2b(wp[j]);
      bf8_t bv = *(const bf8_t*)(y_lds + (32 * qt + l31) * 72 + 16 * kk + 8 * hi);
      oacc = mfma32(av, bv, oacc);
    }
    #pragma unroll
    for (int r = 0; r < 16; ++r) {
      int c = 32 * ct + (r & 3) + 8 * (r >> 2) + 4 * hi;
      size_t gi = ((size_t)b * CH + c) * N_PIX + q0 + 32 * qt + l31;
      out[gi] = oacc[r] + ob[c] + x[gi];
    }
  }
  __syncthreads();

  // ================= epilogue pass B (q0+64 .. q0+127) ====================
  #pragma unroll
  for (int ot = 0; ot < 2; ++ot)
    #pragma unroll
    for (int r = 0; r < 16; ++r) {
      int o = 32 * ot + (r & 3) + 8 * (r >> 2) + 4 * hi;
      smem[(((qg * 4 + mh) * 64 + o) << 5) + l31] = f2b(yaccB[ot][r]);
    }
  if (hi == 0) {
    ml[(qg * 4 + mh) * 64 + l31]      = mB;
    ml[(qg * 4 + mh) * 64 + 32 + l31] = lB;
  }
  __syncthreads();
  {
    const int qg2 = tid >> 8;
    const int rem = tid & 255;
    const int qq  = rem & 31;
    const int og  = rem >> 5;
    float mi[4], li[4];
    #pragma unroll
    for (int i = 0; i < 4; ++i) {
      mi[i] = ml[(qg2 * 4 + i) * 64 + qq];
      li[i] = ml[(qg2 * 4 + i) * 64 + 32 + qq];
    }
    float M = fmaxf(fmaxf(mi[0], mi[1]), fmaxf(mi[2], mi[3]));
    float e[4], L = 0.f;
    #pragma unroll
    for (int i = 0; i < 4; ++i) { e[i] = EXP2(mi[i] - M); L += li[i] * e[i]; }
    float invL = 1.0f / L;
    float acc[8];
    #pragma unroll
    for (int oo = 0; oo < 8; ++oo) {
      int o = og * 8 + oo;
      float a = 0.f;
      #pragma unroll
      for (int i = 0; i < 4; ++i)
        a += b2f(smem[(((qg2 * 4 + i) * 64 + o) << 5) + qq]) * e[i];
      acc[oo] = a * invL;
    }
    uint4 ov;
    ov.x = pack2(acc[0], acc[1]);
    ov.y = pack2(acc[2], acc[3]);
    ov.z = pack2(acc[4], acc[5]);
    ov.w = pack2(acc[6], acc[7]);
    *(uint4*)(y_lds + (32 * qg2 + qq) * 72 + og * 8) = ov;
  }
  __syncthreads();
  {
    const int ct = w & 3;
    const int qt = w >> 2;
    f16v oacc;
    #pragma unroll
    for (int r = 0; r < 16; ++r) oacc[r] = 0.f;
    #pragma unroll
    for (int kk = 0; kk < 4; ++kk) {
      const float* wp = ow + (size_t)(32 * ct + l31) * DD + 16 * kk + 8 * hi;
      bf8_t av;
      #pragma unroll
      for (int j = 0; j < 8; ++j) av[j] = (short)f2b(wp[j]);
      bf8_t bv = *(const bf8_t*)(y_lds + (32 * qt + l31) * 72 + 16 * kk + 8 * hi);
      oacc = mfma32(av, bv, oacc);
    }
    #pragma unroll
    for (int r = 0; r < 16; ++r) {
      int c = 32 * ct + (r & 3) + 8 * (r >> 2) + 4 * hi;
      size_t gi = ((size_t)b * CH + c) * N_PIX + q0 + 64 + 32 * qt + l31;
      out[gi] = oacc[r] + ob[c] + x[gi];
    }
  }
}

extern "C" void kernel_launch(void* const* d_in, const int* in_sizes, int n_in,
                              void* d_out, int out_size, void* d_ws, size_t ws_size,
                              hipStream_t stream) {
  const float* x  = (const float*)d_in[0];
  const float* tw = (const float*)d_in[1];
  const float* tb = (const float*)d_in[2];
  const float* pw = (const float*)d_in[3];
  const float* pb = (const float*)d_in[4];
  const float* gw = (const float*)d_in[5];
  const float* gb = (const float*)d_in[6];
  const float* ow = (const float*)d_in[7];
  const float* ob = (const float*)d_in[8];
  float* out = (float*)d_out;

  const size_t sz = (size_t)NBATCH * N_PIX * DD;   // elems per bf16 tensor
  u16* theta_h = (u16*)d_ws;
  u16* phi_h   = theta_h + sz;
  u16* gt_h    = phi_h + sz;

  proj_kernel<<<512, 256, 0, stream>>>(x, tw, tb, pw, pb, gw, gb,
                                       theta_h, phi_h, gt_h);
  attn_kernel<<<256, 512, 0, stream>>>(theta_h, phi_h, gt_h, ow, ob, x, out);
}